// Round 9
// baseline (396.097 us; speedup 1.0000x reference)
//
#include <hip/hip_runtime.h>

#define DD 64
#define ALPHA 0.6f
#define KHOPS 8
#define WP 72   // LDS row stride in bf16 elems (144 B = 9*16B: aligned, 2-way banks)

typedef __attribute__((ext_vector_type(8))) short bf16x8;
typedef __attribute__((ext_vector_type(4))) float f32x4;

static __device__ __forceinline__ unsigned short f2bf(float f) {
    unsigned int u = __float_as_uint(f);
    unsigned int r = (u + 0x7FFFu + ((u >> 16) & 1u)) >> 16;   // RTN-even
    return (unsigned short)r;
}
static __device__ __forceinline__ unsigned int pack2bf(float lo, float hi) {
    return (unsigned int)f2bf(lo) | ((unsigned int)f2bf(hi) << 16);
}

// zero n16 uint4s
__global__ __launch_bounds__(256) void zero_kernel(uint4* __restrict__ p, int n16) {
    int i = blockIdx.x * blockDim.x + threadIdx.x;
    if (i < n16) p[i] = make_uint4(0u, 0u, 0u, 0u);
}

// XCD-partitioned degree count (cnt lines stay in one XCD's L2)
#define FCHUNK 2048
__global__ __launch_bounds__(256) void deg_count_kernel(const int* __restrict__ dst,
                                                        int* __restrict__ cnt,
                                                        int e, int n) {
    int xcd = blockIdx.x & 7;
    int chunk = blockIdx.x >> 3;
    int lo = (int)(((long long)n * xcd) >> 3);
    int hi = (int)(((long long)n * (xcd + 1)) >> 3);
    int base = chunk * FCHUNK + threadIdx.x * 8;
    if (base >= e) return;
    int4 d0 = *(const int4*)(dst + base);
    int4 d1 = *(const int4*)(dst + base + 4);
    int dv[8] = {d0.x, d0.y, d0.z, d0.w, d1.x, d1.y, d1.z, d1.w};
    #pragma unroll
    for (int j = 0; j < 8; ++j) {
        if (base + j < e) {
            int d = dv[j];
            if (d >= lo && d < hi) atomicAdd(&cnt[d], 1);
        }
    }
}

// ---- hierarchical exclusive scan of cnt -> rowptr, cursor (+ dinvr fused) ----
__global__ __launch_bounds__(256) void scan1_kernel(const int* __restrict__ cnt,
                                                    int* __restrict__ partials,
                                                    float2* __restrict__ dinvr, int n) {
    int i = blockIdx.x * 256 + threadIdx.x;
    int v = (i < n) ? cnt[i] : 0;
    if (i < n) {
        float d = (float)(v + 1);
        dinvr[i] = make_float2(rsqrtf(d), sqrtf(d));
    }
    int sum = v;
    #pragma unroll
    for (int off = 1; off < 64; off <<= 1) sum += __shfl_down(sum, off, 64);
    __shared__ int ws[4];
    if ((threadIdx.x & 63) == 0) ws[threadIdx.x >> 6] = sum;
    __syncthreads();
    if (threadIdx.x == 0) partials[blockIdx.x] = ws[0] + ws[1] + ws[2] + ws[3];
}

__global__ __launch_bounds__(1024) void scan2_kernel(int* __restrict__ partials, int nb) {
    __shared__ int s[1024];
    int t = threadIdx.x;
    int v = (t < nb) ? partials[t] : 0;
    s[t] = v;
    __syncthreads();
    for (int off = 1; off < 1024; off <<= 1) {
        int tmp = (t >= off) ? s[t - off] : 0;
        __syncthreads();
        s[t] += tmp;
        __syncthreads();
    }
    if (t < nb) partials[t] = s[t] - v;   // exclusive
}

__global__ __launch_bounds__(256) void scan3_kernel(const int* __restrict__ cnt,
                                                    const int* __restrict__ partials,
                                                    int* __restrict__ rowptr,
                                                    int* __restrict__ cursor, int n) {
    int t = threadIdx.x;
    int i = blockIdx.x * 256 + t;
    int v = (i < n) ? cnt[i] : 0;
    int lane = t & 63;
    int incl = v;
    #pragma unroll
    for (int off = 1; off < 64; off <<= 1) {
        int u = __shfl_up(incl, off, 64);
        if (lane >= off) incl += u;
    }
    __shared__ int wsum[4];
    if (lane == 63) wsum[t >> 6] = incl;
    __syncthreads();
    int woff = 0;
    for (int w = 0; w < (t >> 6); ++w) woff += wsum[w];
    int excl = incl - v + woff + partials[blockIdx.x];
    if (i < n) { rowptr[i] = excl; cursor[i] = excl; }
    if (i == n - 1) rowptr[n] = excl + v;
}

// XCD-partitioned CSR fill (L2-local esrc/cursor lines)
__global__ __launch_bounds__(256) void fill_kernel(const int* __restrict__ src,
                                                   const int* __restrict__ dst,
                                                   int* __restrict__ cursor,
                                                   int* __restrict__ esrc, int e, int n) {
    int xcd = blockIdx.x & 7;
    int chunk = blockIdx.x >> 3;
    int lo = (int)(((long long)n * xcd) >> 3);
    int hi = (int)(((long long)n * (xcd + 1)) >> 3);
    int base = chunk * FCHUNK + threadIdx.x * 8;
    if (base >= e) return;
    int4 s0 = *(const int4*)(src + base);
    int4 s1 = *(const int4*)(src + base + 4);
    int4 d0 = *(const int4*)(dst + base);
    int4 d1 = *(const int4*)(dst + base + 4);
    int sv[8] = {s0.x, s0.y, s0.z, s0.w, s1.x, s1.y, s1.z, s1.w};
    int dv[8] = {d0.x, d0.y, d0.z, d0.w, d1.x, d1.y, d1.z, d1.w};
    #pragma unroll
    for (int j = 0; j < 8; ++j) {
        if (base + j < e) {
            int d = dv[j];
            if (d >= lo && d < hi) {
                int pos = atomicAdd(&cursor[d], 1);
                esrc[pos] = sv[j];
            }
        }
    }
}

// h = ALPHA*x (f32, row-major) ; y0 = bf16(dinv*x) in SLICE-MAJOR layout:
// y[sl][node][32] bf16, sl = feature-half. 64 B per (node,slice) = one line.
__global__ __launch_bounds__(256) void init_kernel(const float4* __restrict__ x,
                                                   const float2* __restrict__ dinvr,
                                                   float4* __restrict__ h,
                                                   unsigned short* __restrict__ yb,
                                                   int n4, int n) {
    int i = blockIdx.x * blockDim.x + threadIdx.x;
    if (i >= n4) return;
    int row = i >> 4;
    int c4 = i & 15;
    float di = dinvr[row].x;
    float4 v = x[i];
    h[i] = make_float4(ALPHA * v.x, ALPHA * v.y, ALPHA * v.z, ALPHA * v.w);
    int sl = c4 >> 3;
    unsigned short* dstp = yb + (size_t)sl * n * 32 + (size_t)row * 32 + (c4 & 7) * 4;
    *(uint2*)dstp = make_uint2(pack2bf(di * v.x, di * v.y), pack2bf(di * v.z, di * v.w));
}

static __device__ __forceinline__ void add8(float* acc, uint4 v) {
    acc[0] += __uint_as_float(v.x << 16);
    acc[1] += __uint_as_float(v.x & 0xffff0000u);
    acc[2] += __uint_as_float(v.y << 16);
    acc[3] += __uint_as_float(v.y & 0xffff0000u);
    acc[4] += __uint_as_float(v.z << 16);
    acc[5] += __uint_as_float(v.z & 0xffff0000u);
    acc[6] += __uint_as_float(v.w << 16);
    acc[7] += __uint_as_float(v.w & 0xffff0000u);
}

// Slice-split y-space hop. XCD x = blockIdx%8 handles slice (x&1) of node
// quarter (x>>1): per-XCD gather footprint = 3.2MB slice + 0.8MB esrc -> L2-resident.
// Wave = 16 groups x 4 lanes; group g gathers edge e0+i*16+g's 64B slice row.
// S = sum_e y[src] + y[node] ; y' = dinv^2*S ; (DO_H) h += coef*(rdeg*yprev + dinv*S)
template <int DO_H, int DO_OUT>
__global__ __launch_bounds__(256) void hop_kernel(const int* __restrict__ rowptr,
                                                  const int* __restrict__ esrc,
                                                  const float2* __restrict__ dinvr,
                                                  const unsigned short* __restrict__ yin,
                                                  unsigned short* __restrict__ yout,
                                                  float* __restrict__ h,
                                                  float coef, int n) {
    int xcd = blockIdx.x & 7;
    int sl = xcd & 1;
    int q = xcd >> 1;
    int qlo = (int)(((long long)n * q) >> 2);
    int qhi = (int)(((long long)n * (q + 1)) >> 2);
    int node = qlo + ((blockIdx.x >> 3) << 2) + (threadIdx.x >> 6);
    if (node >= qhi) return;
    int lane = threadIdx.x & 63;
    int g = lane >> 2;
    int s = lane & 3;

    const unsigned short* ybase = yin + (size_t)sl * n * 32;

    int e0 = rowptr[node];
    int e1 = rowptr[node + 1];

    float acc[8] = {0.f, 0.f, 0.f, 0.f, 0.f, 0.f, 0.f, 0.f};
    float yprev[8];
    float2 dr;

    if (g == 0) {   // self term (weight 1 in y-space) + epilogue scalars, lanes 0-3
        dr = dinvr[node];
        uint4 v = *(const uint4*)(ybase + (size_t)node * 32 + s * 8);
        yprev[0] = __uint_as_float(v.x << 16);
        yprev[1] = __uint_as_float(v.x & 0xffff0000u);
        yprev[2] = __uint_as_float(v.y << 16);
        yprev[3] = __uint_as_float(v.y & 0xffff0000u);
        yprev[4] = __uint_as_float(v.z << 16);
        yprev[5] = __uint_as_float(v.z & 0xffff0000u);
        yprev[6] = __uint_as_float(v.w << 16);
        yprev[7] = __uint_as_float(v.w & 0xffff0000u);
        #pragma unroll
        for (int j = 0; j < 8; ++j) acc[j] = yprev[j];
    }

    int deg = e1 - e0;
    int niter = (deg + 15) >> 4;    // 16 edges per iteration
    int clampe = e1 - 1;
    for (int i = 0; i < niter; i += 2) {
        int eA = e0 + (i << 4) + g;
        int eB = eA + 16;
        bool vA = eA < e1, vB = eB < e1;
        int sA = esrc[vA ? eA : clampe];
        int sB = esrc[vB ? eB : clampe];
        uint4 va = *(const uint4*)(ybase + (size_t)sA * 32 + s * 8);
        uint4 vb = *(const uint4*)(ybase + (size_t)sB * 32 + s * 8);
        if (!vA) va = make_uint4(0u, 0u, 0u, 0u);
        if (!vB) vb = make_uint4(0u, 0u, 0u, 0u);
        add8(acc, va);
        add8(acc, vb);
    }

    // fold 16 group partials (xor over lane bits 2..5; s preserved)
    #pragma unroll
    for (int off = 4; off < 64; off <<= 1) {
        #pragma unroll
        for (int j = 0; j < 8; ++j) acc[j] += __shfl_xor(acc[j], off, 64);
    }

    if (g == 0) {
        float di = dr.x;
        float d2 = di * di;
        if (DO_OUT) {
            uint4 o;
            o.x = pack2bf(d2 * acc[0], d2 * acc[1]);
            o.y = pack2bf(d2 * acc[2], d2 * acc[3]);
            o.z = pack2bf(d2 * acc[4], d2 * acc[5]);
            o.w = pack2bf(d2 * acc[6], d2 * acc[7]);
            *(uint4*)(yout + (size_t)sl * n * 32 + (size_t)node * 32 + s * 8) = o;
        }
        if (DO_H) {
            float rd = dr.y;
            float* hp = h + (size_t)node * 64 + sl * 32 + s * 8;
            float4 h0 = *(float4*)hp;
            float4 h1 = *(float4*)(hp + 4);
            h0.x += coef * (rd * yprev[0] + di * acc[0]);
            h0.y += coef * (rd * yprev[1] + di * acc[1]);
            h0.z += coef * (rd * yprev[2] + di * acc[2]);
            h0.w += coef * (rd * yprev[3] + di * acc[3]);
            h1.x += coef * (rd * yprev[4] + di * acc[4]);
            h1.y += coef * (rd * yprev[5] + di * acc[5]);
            h1.z += coef * (rd * yprev[6] + di * acc[6]);
            h1.w += coef * (rd * yprev[7] + di * acc[7]);
            *(float4*)hp = h0;
            *(float4*)(hp + 4) = h1;
        }
    }
}

// MFMA fused MLP: out = relu(relu(h Wc^T+bc) W1^T+b1) W2^T+b2
__global__ __launch_bounds__(256) void mlp_mfma_kernel(const float* __restrict__ hin,
                                                       const float* __restrict__ wc,
                                                       const float* __restrict__ bc,
                                                       const float* __restrict__ w1,
                                                       const float* __restrict__ b1,
                                                       const float* __restrict__ w2,
                                                       const float* __restrict__ b2,
                                                       float* __restrict__ out, int n) {
    __shared__ unsigned short wlds[3][64][WP];
    __shared__ unsigned short xlds[64][WP];
    int t = threadIdx.x;

    const float* wm[3] = {wc, w1, w2};
    #pragma unroll
    for (int m = 0; m < 3; ++m) {
        const float4* w4 = (const float4*)wm[m];
        #pragma unroll
        for (int k = 0; k < 4; ++k) {
            int fid = t + k * 256;               // 0..1023 float4s
            int j = fid >> 4, c4 = fid & 15;
            float4 v = w4[fid];
            *(uint2*)&wlds[m][j][c4 * 4] =
                make_uint2(pack2bf(v.x, v.y), pack2bf(v.z, v.w));
        }
    }

    int r0 = blockIdx.x * 64;
    const float4* h4 = (const float4*)hin;
    #pragma unroll
    for (int k = 0; k < 4; ++k) {
        int fid = t + k * 256;
        int r = fid >> 4, c4 = fid & 15;
        int gr = r0 + r;
        float4 v = (gr < n) ? h4[(size_t)gr * 16 + c4]
                            : make_float4(0.f, 0.f, 0.f, 0.f);
        *(uint2*)&xlds[r][c4 * 4] = make_uint2(pack2bf(v.x, v.y), pack2bf(v.z, v.w));
    }
    __syncthreads();

    int lane = t & 63;
    int wv = t >> 6;
    int rbase = wv * 16;
    int lr = lane & 15;
    int kg = lane >> 4;
    const float* bias[3] = {bc, b1, b2};

    #pragma unroll
    for (int m = 0; m < 3; ++m) {
        bf16x8 a0 = *(bf16x8*)&xlds[rbase + lr][kg * 8];
        bf16x8 a1 = *(bf16x8*)&xlds[rbase + lr][32 + kg * 8];
        #pragma unroll
        for (int ct = 0; ct < 4; ++ct) {
            bf16x8 bv0 = *(bf16x8*)&wlds[m][ct * 16 + lr][kg * 8];
            bf16x8 bv1 = *(bf16x8*)&wlds[m][ct * 16 + lr][32 + kg * 8];
            f32x4 acc = {0.f, 0.f, 0.f, 0.f};
            acc = __builtin_amdgcn_mfma_f32_16x16x32_bf16(a0, bv0, acc, 0, 0, 0);
            acc = __builtin_amdgcn_mfma_f32_16x16x32_bf16(a1, bv1, acc, 0, 0, 0);
            float bb = bias[m][ct * 16 + lr];
            if (m < 2) {
                #pragma unroll
                for (int rg = 0; rg < 4; ++rg) {
                    float v = fmaxf(acc[rg] + bb, 0.0f);
                    xlds[rbase + kg * 4 + rg][ct * 16 + lr] = f2bf(v);
                }
            } else {
                #pragma unroll
                for (int rg = 0; rg < 4; ++rg) {
                    int gr = r0 + rbase + kg * 4 + rg;
                    if (gr < n) out[(size_t)gr * 64 + ct * 16 + lr] = acc[rg] + bb;
                }
            }
        }
        // wave reads only its own 16 rows next layer: program order suffices
    }
}

extern "C" void kernel_launch(void* const* d_in, const int* in_sizes, int n_in,
                              void* d_out, int out_size, void* d_ws, size_t ws_size,
                              hipStream_t stream) {
    const float* x      = (const float*)d_in[0];
    const float* w_conv = (const float*)d_in[1];
    const float* b_conv = (const float*)d_in[2];
    const float* w1     = (const float*)d_in[3];
    const float* b1     = (const float*)d_in[4];
    const float* w2     = (const float*)d_in[5];
    const float* b2     = (const float*)d_in[6];
    const int*   ei     = (const int*)d_in[7];

    int n = in_sizes[0] / DD;       // 50000
    int e = in_sizes[7] / 2;        // 800000
    const int* src = ei;
    const int* dst = ei + e;

    // workspace layout (explicit byte offsets)
    char* wsb = (char*)d_ws;
    int*    cnt      = (int*)(wsb + 0);                       // 256 KB slot
    float2* dinvr    = (float2*)(wsb + 256 * 1024);           // 512 KB slot
    int*    rowptr   = (int*)(wsb + 768 * 1024);              // 256 KB slot
    int*    cursor   = (int*)(wsb + 1024 * 1024);             // 256 KB slot
    int*    partials = (int*)(wsb + 1280 * 1024);             // 64 KB slot
    int*    esrc     = (int*)(wsb + 1344 * 1024);             // e*4 = 3.2 MB
    unsigned short* yb0 = (unsigned short*)(wsb + 1344 * 1024 + (size_t)e * 4);
    unsigned short* yb1 = yb0 + (size_t)n * DD;               // 6.4 MB each
    float* h = (float*)d_out;

    const int B = 256;
    int n4 = n * (DD / 4);
    int nb = (n + 255) / 256;
    int nchunks = (e + FCHUNK - 1) / FCHUNK;

    int n16 = (n + 3) / 4;
    zero_kernel<<<(n16 + B - 1) / B, B, 0, stream>>>((uint4*)cnt, n16);
    deg_count_kernel<<<nchunks * 8, B, 0, stream>>>(dst, cnt, e, n);
    scan1_kernel<<<nb, B, 0, stream>>>(cnt, partials, dinvr, n);
    scan2_kernel<<<1, 1024, 0, stream>>>(partials, nb);
    scan3_kernel<<<nb, B, 0, stream>>>(cnt, partials, rowptr, cursor, n);
    fill_kernel<<<nchunks * 8, B, 0, stream>>>(src, dst, cursor, esrc, e, n);

    init_kernel<<<(n4 + B - 1) / B, B, 0, stream>>>(
        (const float4*)x, dinvr, (float4*)h, yb0, n4, n);

    float coef = (1.0f - ALPHA) / (float)KHOPS;
    int qmax = (n + 3) >> 2;                 // max nodes per quarter
    int bpx = (qmax + 3) >> 2;               // blocks per XCD (4 nodes/block)
    int hgrid = bpx * 8;

    unsigned short* cur = yb0;
    unsigned short* nxt = yb1;
    for (int k = 1; k <= KHOPS; ++k) {
        if (k == KHOPS)
            hop_kernel<1, 0><<<hgrid, B, 0, stream>>>(rowptr, esrc, dinvr, cur, nxt,
                                                      h, coef, n);
        else if (k % 2 == 0)
            hop_kernel<1, 1><<<hgrid, B, 0, stream>>>(rowptr, esrc, dinvr, cur, nxt,
                                                      h, coef, n);
        else
            hop_kernel<0, 1><<<hgrid, B, 0, stream>>>(rowptr, esrc, dinvr, cur, nxt,
                                                      h, coef, n);
        unsigned short* tmp = cur; cur = nxt; nxt = tmp;
    }

    mlp_mfma_kernel<<<(n + 63) / 64, B, 0, stream>>>(h, w_conv, b_conv, w1, b1,
                                                     w2, b2, (float*)d_out, n);
}

// Round 10
// 301.665 us; speedup vs baseline: 1.3130x; 1.3130x over previous
//
#include <hip/hip_runtime.h>

#define DD 64
#define ALPHA 0.6f
#define KHOPS 8
#define WP 72   // LDS row stride in bf16 elems (144 B = 9*16B: aligned, 2-way banks)

typedef __attribute__((ext_vector_type(8))) short bf16x8;
typedef __attribute__((ext_vector_type(4))) float f32x4;
typedef __attribute__((ext_vector_type(4))) unsigned int u32x4;

static __device__ __forceinline__ unsigned short f2bf(float f) {
    unsigned int u = __float_as_uint(f);
    unsigned int r = (u + 0x7FFFu + ((u >> 16) & 1u)) >> 16;   // RTN-even
    return (unsigned short)r;
}
static __device__ __forceinline__ unsigned int pack2bf(float lo, float hi) {
    return (unsigned int)f2bf(lo) | ((unsigned int)f2bf(hi) << 16);
}

// zero n16 uint4s
__global__ __launch_bounds__(256) void zero_kernel(uint4* __restrict__ p, int n16) {
    int i = blockIdx.x * blockDim.x + threadIdx.x;
    if (i < n16) p[i] = make_uint4(0u, 0u, 0u, 0u);
}

// XCD-partitioned degree count (cnt lines stay in one XCD's L2)
#define FCHUNK 2048
__global__ __launch_bounds__(256) void deg_count_kernel(const int* __restrict__ dst,
                                                        int* __restrict__ cnt,
                                                        int e, int n) {
    int xcd = blockIdx.x & 7;
    int chunk = blockIdx.x >> 3;
    int lo = (int)(((long long)n * xcd) >> 3);
    int hi = (int)(((long long)n * (xcd + 1)) >> 3);
    int base = chunk * FCHUNK + threadIdx.x * 8;
    if (base >= e) return;
    int4 d0 = *(const int4*)(dst + base);
    int4 d1 = *(const int4*)(dst + base + 4);
    int dv[8] = {d0.x, d0.y, d0.z, d0.w, d1.x, d1.y, d1.z, d1.w};
    #pragma unroll
    for (int j = 0; j < 8; ++j) {
        if (base + j < e) {
            int d = dv[j];
            if (d >= lo && d < hi) atomicAdd(&cnt[d], 1);
        }
    }
}

// ---- hierarchical exclusive scan of cnt -> rowptr, cursor (+ dinvr fused) ----
__global__ __launch_bounds__(256) void scan1_kernel(const int* __restrict__ cnt,
                                                    int* __restrict__ partials,
                                                    float2* __restrict__ dinvr, int n) {
    int i = blockIdx.x * 256 + threadIdx.x;
    int v = (i < n) ? cnt[i] : 0;
    if (i < n) {
        float d = (float)(v + 1);
        dinvr[i] = make_float2(rsqrtf(d), sqrtf(d));
    }
    int sum = v;
    #pragma unroll
    for (int off = 1; off < 64; off <<= 1) sum += __shfl_down(sum, off, 64);
    __shared__ int ws[4];
    if ((threadIdx.x & 63) == 0) ws[threadIdx.x >> 6] = sum;
    __syncthreads();
    if (threadIdx.x == 0) partials[blockIdx.x] = ws[0] + ws[1] + ws[2] + ws[3];
}

__global__ __launch_bounds__(1024) void scan2_kernel(int* __restrict__ partials, int nb) {
    __shared__ int s[1024];
    int t = threadIdx.x;
    int v = (t < nb) ? partials[t] : 0;
    s[t] = v;
    __syncthreads();
    for (int off = 1; off < 1024; off <<= 1) {
        int tmp = (t >= off) ? s[t - off] : 0;
        __syncthreads();
        s[t] += tmp;
        __syncthreads();
    }
    if (t < nb) partials[t] = s[t] - v;   // exclusive
}

__global__ __launch_bounds__(256) void scan3_kernel(const int* __restrict__ cnt,
                                                    const int* __restrict__ partials,
                                                    int* __restrict__ rowptr,
                                                    int* __restrict__ cursor, int n) {
    int t = threadIdx.x;
    int i = blockIdx.x * 256 + t;
    int v = (i < n) ? cnt[i] : 0;
    int lane = t & 63;
    int incl = v;
    #pragma unroll
    for (int off = 1; off < 64; off <<= 1) {
        int u = __shfl_up(incl, off, 64);
        if (lane >= off) incl += u;
    }
    __shared__ int wsum[4];
    if (lane == 63) wsum[t >> 6] = incl;
    __syncthreads();
    int woff = 0;
    for (int w = 0; w < (t >> 6); ++w) woff += wsum[w];
    int excl = incl - v + woff + partials[blockIdx.x];
    if (i < n) { rowptr[i] = excl; cursor[i] = excl; }
    if (i == n - 1) rowptr[n] = excl + v;
}

// XCD-partitioned CSR fill (L2-local esrc/cursor lines)
__global__ __launch_bounds__(256) void fill_kernel(const int* __restrict__ src,
                                                   const int* __restrict__ dst,
                                                   int* __restrict__ cursor,
                                                   int* __restrict__ esrc, int e, int n) {
    int xcd = blockIdx.x & 7;
    int chunk = blockIdx.x >> 3;
    int lo = (int)(((long long)n * xcd) >> 3);
    int hi = (int)(((long long)n * (xcd + 1)) >> 3);
    int base = chunk * FCHUNK + threadIdx.x * 8;
    if (base >= e) return;
    int4 s0 = *(const int4*)(src + base);
    int4 s1 = *(const int4*)(src + base + 4);
    int4 d0 = *(const int4*)(dst + base);
    int4 d1 = *(const int4*)(dst + base + 4);
    int sv[8] = {s0.x, s0.y, s0.z, s0.w, s1.x, s1.y, s1.z, s1.w};
    int dv[8] = {d0.x, d0.y, d0.z, d0.w, d1.x, d1.y, d1.z, d1.w};
    #pragma unroll
    for (int j = 0; j < 8; ++j) {
        if (base + j < e) {
            int d = dv[j];
            if (d >= lo && d < hi) {
                int pos = atomicAdd(&cursor[d], 1);
                esrc[pos] = sv[j];
            }
        }
    }
}

// h = ALPHA*x (f32, nt) ; y0 = bf16(dinv * x) row-major
__global__ __launch_bounds__(256) void init_kernel(const float4* __restrict__ x,
                                                   const float2* __restrict__ dinvr,
                                                   float* __restrict__ h,
                                                   ushort4* __restrict__ yb, int n4) {
    int i = blockIdx.x * blockDim.x + threadIdx.x;
    if (i >= n4) return;
    int row = i >> 4;
    float di = dinvr[row].x;
    float4 v = x[i];
    f32x4 hv = {ALPHA * v.x, ALPHA * v.y, ALPHA * v.z, ALPHA * v.w};
    __builtin_nontemporal_store(hv, (f32x4*)(h + (size_t)i * 4));
    ushort4 b;
    b.x = f2bf(di * v.x); b.y = f2bf(di * v.y);
    b.z = f2bf(di * v.z); b.w = f2bf(di * v.w);
    yb[i] = b;
}

static __device__ __forceinline__ void add8(float* acc, uint4 v) {
    acc[0] += __uint_as_float(v.x << 16);
    acc[1] += __uint_as_float(v.x & 0xffff0000u);
    acc[2] += __uint_as_float(v.y << 16);
    acc[3] += __uint_as_float(v.y & 0xffff0000u);
    acc[4] += __uint_as_float(v.z << 16);
    acc[5] += __uint_as_float(v.z & 0xffff0000u);
    acc[6] += __uint_as_float(v.w << 16);
    acc[7] += __uint_as_float(v.w & 0xffff0000u);
}

// y-space hop (round-8 structure): S = sum_e y[src] + y[node]; y' = dinv^2*S;
// (DO_H) h += coef*(rdeg*yprev + dinv*S). One wave per node; 8 groups x 8 lanes;
// 4 masked octets in flight. NT for h/y-out stores and esrc stream: keep L2 for
// the y-in gather lines (latency-bound fix).
template <int DO_H, int DO_OUT>
__global__ __launch_bounds__(256) void hop_kernel(const int* __restrict__ rowptr,
                                                  const int* __restrict__ esrc,
                                                  const float2* __restrict__ dinvr,
                                                  const unsigned short* __restrict__ yin,
                                                  unsigned short* __restrict__ yout,
                                                  float* __restrict__ h,
                                                  float coef, int n) {
    int wid = (blockIdx.x * blockDim.x + threadIdx.x) >> 6;   // wave id = node
    if (wid >= n) return;
    int lane = threadIdx.x & 63;
    int g = lane >> 3;
    int s = lane & 7;
    int node = wid;

    int e0 = rowptr[node];
    int e1 = rowptr[node + 1];

    float acc[8] = {0.f, 0.f, 0.f, 0.f, 0.f, 0.f, 0.f, 0.f};
    float yprev[8];
    float2 dr;

    if (g == 0) {   // self term (weight 1 in y-space) + epilogue scalars
        dr = dinvr[node];
        uint4 v = *(const uint4*)(yin + (size_t)node * 64 + s * 8);
        yprev[0] = __uint_as_float(v.x << 16);
        yprev[1] = __uint_as_float(v.x & 0xffff0000u);
        yprev[2] = __uint_as_float(v.y << 16);
        yprev[3] = __uint_as_float(v.y & 0xffff0000u);
        yprev[4] = __uint_as_float(v.z << 16);
        yprev[5] = __uint_as_float(v.z & 0xffff0000u);
        yprev[6] = __uint_as_float(v.w << 16);
        yprev[7] = __uint_as_float(v.w & 0xffff0000u);
        #pragma unroll
        for (int j = 0; j < 8; ++j) acc[j] = yprev[j];
    }

    int deg = e1 - e0;
    int niter = (deg + 7) >> 3;     // octet count
    int clampe = e1 - 1;
    for (int i = 0; i < niter; i += 4) {
        int eA = e0 + (i << 3) + g;
        int eB = eA + 8, eC = eA + 16, eD = eA + 24;
        bool vA = eA < e1, vB = eB < e1, vC = eC < e1, vD = eD < e1;
        int sA = __builtin_nontemporal_load(esrc + (vA ? eA : clampe));
        int sB = __builtin_nontemporal_load(esrc + (vB ? eB : clampe));
        int sC = __builtin_nontemporal_load(esrc + (vC ? eC : clampe));
        int sD = __builtin_nontemporal_load(esrc + (vD ? eD : clampe));
        uint4 va = *(const uint4*)(yin + (size_t)sA * 64 + s * 8);
        uint4 vb = *(const uint4*)(yin + (size_t)sB * 64 + s * 8);
        uint4 vc = *(const uint4*)(yin + (size_t)sC * 64 + s * 8);
        uint4 vd = *(const uint4*)(yin + (size_t)sD * 64 + s * 8);
        if (!vA) va = make_uint4(0u, 0u, 0u, 0u);
        if (!vB) vb = make_uint4(0u, 0u, 0u, 0u);
        if (!vC) vc = make_uint4(0u, 0u, 0u, 0u);
        if (!vD) vd = make_uint4(0u, 0u, 0u, 0u);
        add8(acc, va);
        add8(acc, vb);
        add8(acc, vc);
        add8(acc, vd);
    }

    #pragma unroll
    for (int off = 8; off < 64; off <<= 1) {
        #pragma unroll
        for (int j = 0; j < 8; ++j) acc[j] += __shfl_xor(acc[j], off, 64);
    }

    if (g == 0) {
        float di = dr.x;
        float d2 = di * di;
        if (DO_OUT) {
            u32x4 o = {pack2bf(d2 * acc[0], d2 * acc[1]),
                       pack2bf(d2 * acc[2], d2 * acc[3]),
                       pack2bf(d2 * acc[4], d2 * acc[5]),
                       pack2bf(d2 * acc[6], d2 * acc[7])};
            __builtin_nontemporal_store(o, (u32x4*)(yout + (size_t)node * 64 + s * 8));
        }
        if (DO_H) {
            float rd = dr.y;
            float* hp = h + (size_t)node * 64 + s * 8;
            f32x4 h0 = __builtin_nontemporal_load((const f32x4*)hp);
            f32x4 h1 = __builtin_nontemporal_load((const f32x4*)(hp + 4));
            h0[0] += coef * (rd * yprev[0] + di * acc[0]);
            h0[1] += coef * (rd * yprev[1] + di * acc[1]);
            h0[2] += coef * (rd * yprev[2] + di * acc[2]);
            h0[3] += coef * (rd * yprev[3] + di * acc[3]);
            h1[0] += coef * (rd * yprev[4] + di * acc[4]);
            h1[1] += coef * (rd * yprev[5] + di * acc[5]);
            h1[2] += coef * (rd * yprev[6] + di * acc[6]);
            h1[3] += coef * (rd * yprev[7] + di * acc[7]);
            __builtin_nontemporal_store(h0, (f32x4*)hp);
            __builtin_nontemporal_store(h1, (f32x4*)(hp + 4));
        }
    }
}

// MFMA fused MLP: out = relu(relu(h Wc^T+bc) W1^T+b1) W2^T+b2
__global__ __launch_bounds__(256) void mlp_mfma_kernel(const float* __restrict__ hin,
                                                       const float* __restrict__ wc,
                                                       const float* __restrict__ bc,
                                                       const float* __restrict__ w1,
                                                       const float* __restrict__ b1,
                                                       const float* __restrict__ w2,
                                                       const float* __restrict__ b2,
                                                       float* __restrict__ out, int n) {
    __shared__ unsigned short wlds[3][64][WP];
    __shared__ unsigned short xlds[64][WP];
    int t = threadIdx.x;

    const float* wm[3] = {wc, w1, w2};
    #pragma unroll
    for (int m = 0; m < 3; ++m) {
        const float4* w4 = (const float4*)wm[m];
        #pragma unroll
        for (int k = 0; k < 4; ++k) {
            int fid = t + k * 256;               // 0..1023 float4s
            int j = fid >> 4, c4 = fid & 15;
            float4 v = w4[fid];
            *(uint2*)&wlds[m][j][c4 * 4] =
                make_uint2(pack2bf(v.x, v.y), pack2bf(v.z, v.w));
        }
    }

    int r0 = blockIdx.x * 64;
    #pragma unroll
    for (int k = 0; k < 4; ++k) {
        int fid = t + k * 256;
        int r = fid >> 4, c4 = fid & 15;
        int gr = r0 + r;
        f32x4 v = {0.f, 0.f, 0.f, 0.f};
        if (gr < n)
            v = __builtin_nontemporal_load(
                    (const f32x4*)(hin + (size_t)gr * 64 + c4 * 4));
        *(uint2*)&xlds[r][c4 * 4] = make_uint2(pack2bf(v[0], v[1]), pack2bf(v[2], v[3]));
    }
    __syncthreads();

    int lane = t & 63;
    int wv = t >> 6;
    int rbase = wv * 16;
    int lr = lane & 15;
    int kg = lane >> 4;
    const float* bias[3] = {bc, b1, b2};

    #pragma unroll
    for (int m = 0; m < 3; ++m) {
        bf16x8 a0 = *(bf16x8*)&xlds[rbase + lr][kg * 8];
        bf16x8 a1 = *(bf16x8*)&xlds[rbase + lr][32 + kg * 8];
        #pragma unroll
        for (int ct = 0; ct < 4; ++ct) {
            bf16x8 bv0 = *(bf16x8*)&wlds[m][ct * 16 + lr][kg * 8];
            bf16x8 bv1 = *(bf16x8*)&wlds[m][ct * 16 + lr][32 + kg * 8];
            f32x4 acc = {0.f, 0.f, 0.f, 0.f};
            acc = __builtin_amdgcn_mfma_f32_16x16x32_bf16(a0, bv0, acc, 0, 0, 0);
            acc = __builtin_amdgcn_mfma_f32_16x16x32_bf16(a1, bv1, acc, 0, 0, 0);
            float bb = bias[m][ct * 16 + lr];
            if (m < 2) {
                #pragma unroll
                for (int rg = 0; rg < 4; ++rg) {
                    float v = fmaxf(acc[rg] + bb, 0.0f);
                    xlds[rbase + kg * 4 + rg][ct * 16 + lr] = f2bf(v);
                }
            } else {
                #pragma unroll
                for (int rg = 0; rg < 4; ++rg) {
                    int gr = r0 + rbase + kg * 4 + rg;
                    if (gr < n) out[(size_t)gr * 64 + ct * 16 + lr] = acc[rg] + bb;
                }
            }
        }
        // wave reads only its own 16 rows next layer: program order suffices
    }
}

extern "C" void kernel_launch(void* const* d_in, const int* in_sizes, int n_in,
                              void* d_out, int out_size, void* d_ws, size_t ws_size,
                              hipStream_t stream) {
    const float* x      = (const float*)d_in[0];
    const float* w_conv = (const float*)d_in[1];
    const float* b_conv = (const float*)d_in[2];
    const float* w1     = (const float*)d_in[3];
    const float* b1     = (const float*)d_in[4];
    const float* w2     = (const float*)d_in[5];
    const float* b2     = (const float*)d_in[6];
    const int*   ei     = (const int*)d_in[7];

    int n = in_sizes[0] / DD;       // 50000
    int e = in_sizes[7] / 2;        // 800000
    const int* src = ei;
    const int* dst = ei + e;

    // workspace layout (explicit byte offsets)
    char* wsb = (char*)d_ws;
    int*    cnt      = (int*)(wsb + 0);                       // 256 KB slot
    float2* dinvr    = (float2*)(wsb + 256 * 1024);           // 512 KB slot
    int*    rowptr   = (int*)(wsb + 768 * 1024);              // 256 KB slot
    int*    cursor   = (int*)(wsb + 1024 * 1024);             // 256 KB slot
    int*    partials = (int*)(wsb + 1280 * 1024);             // 64 KB slot
    int*    esrc     = (int*)(wsb + 1344 * 1024);             // e*4 = 3.2 MB
    unsigned short* yb0 = (unsigned short*)(wsb + 1344 * 1024 + (size_t)e * 4);
    unsigned short* yb1 = yb0 + (size_t)n * DD;               // 6.4 MB each
    float* h = (float*)d_out;

    const int B = 256;
    int n4 = n * (DD / 4);
    int nb = (n + 255) / 256;
    int nchunks = (e + FCHUNK - 1) / FCHUNK;

    int n16 = (n + 3) / 4;
    zero_kernel<<<(n16 + B - 1) / B, B, 0, stream>>>((uint4*)cnt, n16);
    deg_count_kernel<<<nchunks * 8, B, 0, stream>>>(dst, cnt, e, n);
    scan1_kernel<<<nb, B, 0, stream>>>(cnt, partials, dinvr, n);
    scan2_kernel<<<1, 1024, 0, stream>>>(partials, nb);
    scan3_kernel<<<nb, B, 0, stream>>>(cnt, partials, rowptr, cursor, n);
    fill_kernel<<<nchunks * 8, B, 0, stream>>>(src, dst, cursor, esrc, e, n);

    init_kernel<<<(n4 + B - 1) / B, B, 0, stream>>>(
        (const float4*)x, dinvr, h, (ushort4*)yb0, n4);

    float coef = (1.0f - ALPHA) / (float)KHOPS;
    int hblocks = (int)(((size_t)n * 64 + B - 1) / B);

    unsigned short* cur = yb0;
    unsigned short* nxt = yb1;
    for (int k = 1; k <= KHOPS; ++k) {
        if (k == KHOPS)
            hop_kernel<1, 0><<<hblocks, B, 0, stream>>>(rowptr, esrc, dinvr, cur, nxt,
                                                        h, coef, n);
        else if (k % 2 == 0)
            hop_kernel<1, 1><<<hblocks, B, 0, stream>>>(rowptr, esrc, dinvr, cur, nxt,
                                                        h, coef, n);
        else
            hop_kernel<0, 1><<<hblocks, B, 0, stream>>>(rowptr, esrc, dinvr, cur, nxt,
                                                        h, coef, n);
        unsigned short* tmp = cur; cur = nxt; nxt = tmp;
    }

    mlp_mfma_kernel<<<(n + 63) / 64, B, 0, stream>>>(h, w_conv, b_conv, w1, b1,
                                                     w2, b2, (float*)d_out, n);
}

// Round 11
// 274.757 us; speedup vs baseline: 1.4416x; 1.0979x over previous
//
#include <hip/hip_runtime.h>

#define DD 64
#define ALPHA 0.6f
#define KHOPS 8
#define WP 72   // LDS row stride in bf16 elems (144 B = 9*16B: aligned, 2-way banks)

typedef __attribute__((ext_vector_type(8))) short bf16x8;
typedef __attribute__((ext_vector_type(4))) float f32x4;

static __device__ __forceinline__ unsigned short f2bf(float f) {
    unsigned int u = __float_as_uint(f);
    unsigned int r = (u + 0x7FFFu + ((u >> 16) & 1u)) >> 16;   // RTN-even
    return (unsigned short)r;
}
static __device__ __forceinline__ unsigned int pack2bf(float lo, float hi) {
    return (unsigned int)f2bf(lo) | ((unsigned int)f2bf(hi) << 16);
}

// zero n16 uint4s
__global__ __launch_bounds__(256) void zero_kernel(uint4* __restrict__ p, int n16) {
    int i = blockIdx.x * blockDim.x + threadIdx.x;
    if (i < n16) p[i] = make_uint4(0u, 0u, 0u, 0u);
}

// XCD-partitioned degree count (cnt lines stay in one XCD's L2)
#define FCHUNK 2048
__global__ __launch_bounds__(256) void deg_count_kernel(const int* __restrict__ dst,
                                                        int* __restrict__ cnt,
                                                        int e, int n) {
    int xcd = blockIdx.x & 7;
    int chunk = blockIdx.x >> 3;
    int lo = (int)(((long long)n * xcd) >> 3);
    int hi = (int)(((long long)n * (xcd + 1)) >> 3);
    int base = chunk * FCHUNK + threadIdx.x * 8;
    if (base >= e) return;
    int4 d0 = *(const int4*)(dst + base);
    int4 d1 = *(const int4*)(dst + base + 4);
    int dv[8] = {d0.x, d0.y, d0.z, d0.w, d1.x, d1.y, d1.z, d1.w};
    #pragma unroll
    for (int j = 0; j < 8; ++j) {
        if (base + j < e) {
            int d = dv[j];
            if (d >= lo && d < hi) atomicAdd(&cnt[d], 1);
        }
    }
}

// ---- hierarchical exclusive scan of cnt -> rowptr, cursor (+ dinvr fused) ----
__global__ __launch_bounds__(256) void scan1_kernel(const int* __restrict__ cnt,
                                                    int* __restrict__ partials,
                                                    float2* __restrict__ dinvr, int n) {
    int i = blockIdx.x * 256 + threadIdx.x;
    int v = (i < n) ? cnt[i] : 0;
    if (i < n) {
        float d = (float)(v + 1);
        dinvr[i] = make_float2(rsqrtf(d), sqrtf(d));
    }
    int sum = v;
    #pragma unroll
    for (int off = 1; off < 64; off <<= 1) sum += __shfl_down(sum, off, 64);
    __shared__ int ws[4];
    if ((threadIdx.x & 63) == 0) ws[threadIdx.x >> 6] = sum;
    __syncthreads();
    if (threadIdx.x == 0) partials[blockIdx.x] = ws[0] + ws[1] + ws[2] + ws[3];
}

__global__ __launch_bounds__(1024) void scan2_kernel(int* __restrict__ partials, int nb) {
    __shared__ int s[1024];
    int t = threadIdx.x;
    int v = (t < nb) ? partials[t] : 0;
    s[t] = v;
    __syncthreads();
    for (int off = 1; off < 1024; off <<= 1) {
        int tmp = (t >= off) ? s[t - off] : 0;
        __syncthreads();
        s[t] += tmp;
        __syncthreads();
    }
    if (t < nb) partials[t] = s[t] - v;   // exclusive
}

__global__ __launch_bounds__(256) void scan3_kernel(const int* __restrict__ cnt,
                                                    const int* __restrict__ partials,
                                                    int* __restrict__ rowptr,
                                                    int* __restrict__ cursor, int n) {
    int t = threadIdx.x;
    int i = blockIdx.x * 256 + t;
    int v = (i < n) ? cnt[i] : 0;
    int lane = t & 63;
    int incl = v;
    #pragma unroll
    for (int off = 1; off < 64; off <<= 1) {
        int u = __shfl_up(incl, off, 64);
        if (lane >= off) incl += u;
    }
    __shared__ int wsum[4];
    if (lane == 63) wsum[t >> 6] = incl;
    __syncthreads();
    int woff = 0;
    for (int w = 0; w < (t >> 6); ++w) woff += wsum[w];
    int excl = incl - v + woff + partials[blockIdx.x];
    if (i < n) { rowptr[i] = excl; cursor[i] = excl; }
    if (i == n - 1) rowptr[n] = excl + v;
}

// XCD-partitioned CSR fill (L2-local esrc/cursor lines)
__global__ __launch_bounds__(256) void fill_kernel(const int* __restrict__ src,
                                                   const int* __restrict__ dst,
                                                   int* __restrict__ cursor,
                                                   int* __restrict__ esrc, int e, int n) {
    int xcd = blockIdx.x & 7;
    int chunk = blockIdx.x >> 3;
    int lo = (int)(((long long)n * xcd) >> 3);
    int hi = (int)(((long long)n * (xcd + 1)) >> 3);
    int base = chunk * FCHUNK + threadIdx.x * 8;
    if (base >= e) return;
    int4 s0 = *(const int4*)(src + base);
    int4 s1 = *(const int4*)(src + base + 4);
    int4 d0 = *(const int4*)(dst + base);
    int4 d1 = *(const int4*)(dst + base + 4);
    int sv[8] = {s0.x, s0.y, s0.z, s0.w, s1.x, s1.y, s1.z, s1.w};
    int dv[8] = {d0.x, d0.y, d0.z, d0.w, d1.x, d1.y, d1.z, d1.w};
    #pragma unroll
    for (int j = 0; j < 8; ++j) {
        if (base + j < e) {
            int d = dv[j];
            if (d >= lo && d < hi) {
                int pos = atomicAdd(&cursor[d], 1);
                esrc[pos] = sv[j];
            }
        }
    }
}

// y0 = bf16(dinv * x)   (h is never materialized: deferred to the MLP)
__global__ __launch_bounds__(256) void init_kernel(const float4* __restrict__ x,
                                                   const float2* __restrict__ dinvr,
                                                   ushort4* __restrict__ yb, int n4) {
    int i = blockIdx.x * blockDim.x + threadIdx.x;
    if (i >= n4) return;
    int row = i >> 4;
    float di = dinvr[row].x;
    float4 v = x[i];
    ushort4 b;
    b.x = f2bf(di * v.x); b.y = f2bf(di * v.y);
    b.z = f2bf(di * v.z); b.w = f2bf(di * v.w);
    yb[i] = b;
}

static __device__ __forceinline__ void add8(float* acc, uint4 v) {
    acc[0] += __uint_as_float(v.x << 16);
    acc[1] += __uint_as_float(v.x & 0xffff0000u);
    acc[2] += __uint_as_float(v.y << 16);
    acc[3] += __uint_as_float(v.y & 0xffff0000u);
    acc[4] += __uint_as_float(v.z << 16);
    acc[5] += __uint_as_float(v.z & 0xffff0000u);
    acc[6] += __uint_as_float(v.w << 16);
    acc[7] += __uint_as_float(v.w & 0xffff0000u);
}

// y-space hop: S = sum_e y[src] + y[node]; y' = dinv^2 * S.  No h work.
// One wave per node; 8 groups x 8 lanes; 4 masked octets in flight.
__global__ __launch_bounds__(256) void hop_kernel(const int* __restrict__ rowptr,
                                                  const int* __restrict__ esrc,
                                                  const float2* __restrict__ dinvr,
                                                  const unsigned short* __restrict__ yin,
                                                  unsigned short* __restrict__ yout,
                                                  int n) {
    int wid = (blockIdx.x * blockDim.x + threadIdx.x) >> 6;   // wave id = node
    if (wid >= n) return;
    int lane = threadIdx.x & 63;
    int g = lane >> 3;
    int s = lane & 7;
    int node = wid;

    int e0 = rowptr[node];
    int e1 = rowptr[node + 1];

    float acc[8] = {0.f, 0.f, 0.f, 0.f, 0.f, 0.f, 0.f, 0.f};
    float d2 = 0.f;

    if (g == 0) {   // self term (weight 1 in y-space)
        float di = dinvr[node].x;
        d2 = di * di;
        uint4 v = *(const uint4*)(yin + (size_t)node * 64 + s * 8);
        add8(acc, v);
    }

    int deg = e1 - e0;
    int niter = (deg + 7) >> 3;     // octet count
    int clampe = e1 - 1;
    for (int i = 0; i < niter; i += 4) {
        int eA = e0 + (i << 3) + g;
        int eB = eA + 8, eC = eA + 16, eD = eA + 24;
        bool vA = eA < e1, vB = eB < e1, vC = eC < e1, vD = eD < e1;
        int sA = esrc[vA ? eA : clampe];
        int sB = esrc[vB ? eB : clampe];
        int sC = esrc[vC ? eC : clampe];
        int sD = esrc[vD ? eD : clampe];
        uint4 va = *(const uint4*)(yin + (size_t)sA * 64 + s * 8);
        uint4 vb = *(const uint4*)(yin + (size_t)sB * 64 + s * 8);
        uint4 vc = *(const uint4*)(yin + (size_t)sC * 64 + s * 8);
        uint4 vd = *(const uint4*)(yin + (size_t)sD * 64 + s * 8);
        if (!vA) va = make_uint4(0u, 0u, 0u, 0u);
        if (!vB) vb = make_uint4(0u, 0u, 0u, 0u);
        if (!vC) vc = make_uint4(0u, 0u, 0u, 0u);
        if (!vD) vd = make_uint4(0u, 0u, 0u, 0u);
        add8(acc, va);
        add8(acc, vb);
        add8(acc, vc);
        add8(acc, vd);
    }

    #pragma unroll
    for (int off = 8; off < 64; off <<= 1) {
        #pragma unroll
        for (int j = 0; j < 8; ++j) acc[j] += __shfl_xor(acc[j], off, 64);
    }

    if (g == 0) {
        uint4 o;
        o.x = pack2bf(d2 * acc[0], d2 * acc[1]);
        o.y = pack2bf(d2 * acc[2], d2 * acc[3]);
        o.z = pack2bf(d2 * acc[4], d2 * acc[5]);
        o.w = pack2bf(d2 * acc[6], d2 * acc[7]);
        *(uint4*)(yout + (size_t)node * 64 + s * 8) = o;
    }
}

// MFMA fused MLP with on-the-fly h:
// h[r][c] = ALPHA*x[r][c] + coef*rdeg[r]*sum_{k=1..8} y_k[r][c]
// then out = relu(relu(h Wc^T+bc) W1^T+b1) W2^T+b2
__global__ __launch_bounds__(256) void mlp_mfma_kernel(const float* __restrict__ x,
                                                       const float2* __restrict__ dinvr,
                                                       const unsigned short* __restrict__ yall,
                                                       size_t ystride, float coef,
                                                       const float* __restrict__ wc,
                                                       const float* __restrict__ bc,
                                                       const float* __restrict__ w1,
                                                       const float* __restrict__ b1,
                                                       const float* __restrict__ w2,
                                                       const float* __restrict__ b2,
                                                       float* __restrict__ out, int n) {
    __shared__ unsigned short wlds[3][64][WP];
    __shared__ unsigned short xlds[64][WP];
    int t = threadIdx.x;

    const float* wm[3] = {wc, w1, w2};
    #pragma unroll
    for (int m = 0; m < 3; ++m) {
        const float4* w4 = (const float4*)wm[m];
        #pragma unroll
        for (int k = 0; k < 4; ++k) {
            int fid = t + k * 256;               // 0..1023 float4s
            int j = fid >> 4, c4 = fid & 15;
            float4 v = w4[fid];
            *(uint2*)&wlds[m][j][c4 * 4] =
                make_uint2(pack2bf(v.x, v.y), pack2bf(v.z, v.w));
        }
    }

    int r0 = blockIdx.x * 64;
    const float4* x4 = (const float4*)x;
    #pragma unroll
    for (int k = 0; k < 4; ++k) {
        int fid = t + k * 256;
        int r = fid >> 4, c4 = fid & 15;
        int gr = r0 + r;
        float h0 = 0.f, h1 = 0.f, h2 = 0.f, h3 = 0.f;
        if (gr < n) {
            float4 xv = x4[(size_t)gr * 16 + c4];
            float ys0 = 0.f, ys1 = 0.f, ys2 = 0.f, ys3 = 0.f;
            #pragma unroll
            for (int kk = 1; kk <= KHOPS; ++kk) {
                uint2 u = *(const uint2*)(yall + (size_t)kk * ystride +
                                          (size_t)gr * 64 + c4 * 4);
                ys0 += __uint_as_float(u.x << 16);
                ys1 += __uint_as_float(u.x & 0xffff0000u);
                ys2 += __uint_as_float(u.y << 16);
                ys3 += __uint_as_float(u.y & 0xffff0000u);
            }
            float cr = coef * dinvr[gr].y;   // coef * rdeg
            h0 = ALPHA * xv.x + cr * ys0;
            h1 = ALPHA * xv.y + cr * ys1;
            h2 = ALPHA * xv.z + cr * ys2;
            h3 = ALPHA * xv.w + cr * ys3;
        }
        *(uint2*)&xlds[r][c4 * 4] = make_uint2(pack2bf(h0, h1), pack2bf(h2, h3));
    }
    __syncthreads();

    int lane = t & 63;
    int wv = t >> 6;
    int rbase = wv * 16;
    int lr = lane & 15;
    int kg = lane >> 4;
    const float* bias[3] = {bc, b1, b2};

    #pragma unroll
    for (int m = 0; m < 3; ++m) {
        bf16x8 a0 = *(bf16x8*)&xlds[rbase + lr][kg * 8];
        bf16x8 a1 = *(bf16x8*)&xlds[rbase + lr][32 + kg * 8];
        #pragma unroll
        for (int ct = 0; ct < 4; ++ct) {
            bf16x8 bv0 = *(bf16x8*)&wlds[m][ct * 16 + lr][kg * 8];
            bf16x8 bv1 = *(bf16x8*)&wlds[m][ct * 16 + lr][32 + kg * 8];
            f32x4 acc = {0.f, 0.f, 0.f, 0.f};
            acc = __builtin_amdgcn_mfma_f32_16x16x32_bf16(a0, bv0, acc, 0, 0, 0);
            acc = __builtin_amdgcn_mfma_f32_16x16x32_bf16(a1, bv1, acc, 0, 0, 0);
            float bb = bias[m][ct * 16 + lr];
            if (m < 2) {
                #pragma unroll
                for (int rg = 0; rg < 4; ++rg) {
                    float v = fmaxf(acc[rg] + bb, 0.0f);
                    xlds[rbase + kg * 4 + rg][ct * 16 + lr] = f2bf(v);
                }
            } else {
                #pragma unroll
                for (int rg = 0; rg < 4; ++rg) {
                    int gr = r0 + rbase + kg * 4 + rg;
                    if (gr < n) out[(size_t)gr * 64 + ct * 16 + lr] = acc[rg] + bb;
                }
            }
        }
        // wave reads only its own 16 rows next layer: program order suffices
    }
}

extern "C" void kernel_launch(void* const* d_in, const int* in_sizes, int n_in,
                              void* d_out, int out_size, void* d_ws, size_t ws_size,
                              hipStream_t stream) {
    const float* x      = (const float*)d_in[0];
    const float* w_conv = (const float*)d_in[1];
    const float* b_conv = (const float*)d_in[2];
    const float* w1     = (const float*)d_in[3];
    const float* b1     = (const float*)d_in[4];
    const float* w2     = (const float*)d_in[5];
    const float* b2     = (const float*)d_in[6];
    const int*   ei     = (const int*)d_in[7];

    int n = in_sizes[0] / DD;       // 50000
    int e = in_sizes[7] / 2;        // 800000
    const int* src = ei;
    const int* dst = ei + e;

    // workspace layout (explicit byte offsets)
    char* wsb = (char*)d_ws;
    int*    cnt      = (int*)(wsb + 0);                       // 256 KB slot
    float2* dinvr    = (float2*)(wsb + 256 * 1024);           // 512 KB slot
    int*    rowptr   = (int*)(wsb + 768 * 1024);              // 256 KB slot
    int*    cursor   = (int*)(wsb + 1024 * 1024);             // 256 KB slot
    int*    partials = (int*)(wsb + 1280 * 1024);             // 64 KB slot
    int*    esrc     = (int*)(wsb + 1344 * 1024);             // e*4 = 3.2 MB
    unsigned short* ybase = (unsigned short*)(wsb + 1344 * 1024 + (size_t)e * 4);
    size_t ystride = (size_t)n * DD;                          // elems per y_k (6.4 MB)
    // y_k = ybase + k*ystride, k = 0..KHOPS  (57.6 MB total)

    const int B = 256;
    int n4 = n * (DD / 4);
    int nb = (n + 255) / 256;
    int nchunks = (e + FCHUNK - 1) / FCHUNK;

    int n16 = (n + 3) / 4;
    zero_kernel<<<(n16 + B - 1) / B, B, 0, stream>>>((uint4*)cnt, n16);
    deg_count_kernel<<<nchunks * 8, B, 0, stream>>>(dst, cnt, e, n);
    scan1_kernel<<<nb, B, 0, stream>>>(cnt, partials, dinvr, n);
    scan2_kernel<<<1, 1024, 0, stream>>>(partials, nb);
    scan3_kernel<<<nb, B, 0, stream>>>(cnt, partials, rowptr, cursor, n);
    fill_kernel<<<nchunks * 8, B, 0, stream>>>(src, dst, cursor, esrc, e, n);

    init_kernel<<<(n4 + B - 1) / B, B, 0, stream>>>(
        (const float4*)x, dinvr, (ushort4*)ybase, n4);

    float coef = (1.0f - ALPHA) / (float)KHOPS;
    int hblocks = (int)(((size_t)n * 64 + B - 1) / B);

    for (int k = 1; k <= KHOPS; ++k) {
        hop_kernel<<<hblocks, B, 0, stream>>>(rowptr, esrc, dinvr,
                                              ybase + (size_t)(k - 1) * ystride,
                                              ybase + (size_t)k * ystride, n);
    }

    mlp_mfma_kernel<<<(n + 63) / 64, B, 0, stream>>>(
        x, dinvr, ybase, ystride, coef, w_conv, b_conv, w1, b1, w2, b2,
        (float*)d_out, n);
}